// Round 7
// baseline (529.540 us; speedup 1.0000x reference)
//
#include <hip/hip_runtime.h>
#include <cstdint>
#include <cstddef>

#define N_INST 8192
#define L_DIM  384
#define D_DIM  128
#define C_CLS  5

typedef __bf16 bf16x8 __attribute__((ext_vector_type(8)));
typedef float  f32x4  __attribute__((ext_vector_type(4)));
// 4-byte-aligned float4 for the dist output (base offset 20 B).
typedef float  f32x4u __attribute__((ext_vector_type(4), aligned(4)));

typedef __attribute__((address_space(1))) void gvoid_t;
typedef __attribute__((address_space(3))) void lvoid_t;

__device__ __forceinline__ unsigned short f2bf(float f) {
  unsigned u = __float_as_uint(f);
  unsigned r = (u + 0x7FFFu + ((u >> 16) & 1u)) >> 16;  // RNE
  return (unsigned short)r;
}
__device__ __forceinline__ float bf2f(unsigned short b) {
  return __uint_as_float(((unsigned)b) << 16);
}

__device__ __forceinline__ void gload_lds16(const void* g, void* lds) {
  __builtin_amdgcn_global_load_lds(
      (gvoid_t*)(uintptr_t)g,
      (lvoid_t*)(uint32_t)(uintptr_t)lds,
      16, 0, 0);
}

// ---- prep: x -> bf16, sq[i] = sum(bf16(x_i)^2) in fp32 -------------------
__global__ __launch_bounds__(256) void prep_x_kernel(
    const float* __restrict__ x, unsigned short* __restrict__ xbf,
    float* __restrict__ sq) {
  int w = threadIdx.x >> 6, lane = threadIdx.x & 63;
  int row = blockIdx.x * 4 + w;
  const float* xr = x + (size_t)row * L_DIM;
  unsigned short* br = xbf + (size_t)row * L_DIM;
  float s = 0.f;
#pragma unroll
  for (int k = 0; k < 6; ++k) {
    float v = xr[lane + 64 * k];
    unsigned short b = f2bf(v);
    br[lane + 64 * k] = b;
    float vb = bf2f(b);
    s = fmaf(vb, vb, s);
  }
#pragma unroll
  for (int off = 32; off; off >>= 1) s += __shfl_down(s, off, 64);
  if (lane == 0) sq[row] = s;
}

// ---- prep: aW1 [384][128] -> aW1T_bf [128][384] --------------------------
__global__ __launch_bounds__(256) void prep_w_kernel(
    const float* __restrict__ aW1, unsigned short* __restrict__ w1t) {
  int idx = blockIdx.x * 256 + threadIdx.x;  // 49152 total
  int d = idx / L_DIM, l = idx - d * L_DIM;
  w1t[idx] = f2bf(aW1[(size_t)l * D_DIM + d]);
}

// ---- attention GEMM: h_tanh[i][d] = tanh(x_bf . aW1T[d] + ab1[d]) --------
__global__ __launch_bounds__(256, 2) void attn_gemm_kernel(
    const unsigned short* __restrict__ amat,   // x_bf [8192][384]
    const unsigned short* __restrict__ bmat,   // aW1T_bf [128][384]
    const float* __restrict__ bias,            // ab1
    float* __restrict__ out) {
  __shared__ alignas(16) unsigned short As[128][64];
  __shared__ alignas(16) unsigned short Bs[128][64];

  int tid = threadIdx.x;
  int w = tid >> 6, lane = tid & 63;
  int wr = w >> 1, wc = w & 1;
  int i0 = blockIdx.x * 128;

  const unsigned short* asrc = amat + (size_t)i0 * L_DIM;
  const unsigned short* bsrc = bmat;

  f32x4 acc[4][4];
#pragma unroll
  for (int m = 0; m < 4; ++m)
#pragma unroll
    for (int n = 0; n < 4; ++n) acc[m][n] = (f32x4){0.f, 0.f, 0.f, 0.f};

  int lrow = lane & 15, lkb = lane >> 4;

  for (int kc = 0; kc < 6; ++kc) {
    int k0 = kc * 64;
#pragma unroll
    for (int c = 0; c < 4; ++c) {
      int rb = c * 32 + w * 8;
      gload_lds16(asrc + (size_t)(rb + (lane >> 3)) * L_DIM + k0 + (lane & 7) * 8,
                  &As[rb][0]);
      gload_lds16(bsrc + (size_t)(rb + (lane >> 3)) * L_DIM + k0 + (lane & 7) * 8,
                  &Bs[rb][0]);
    }
    __syncthreads();
#pragma unroll
    for (int kk = 0; kk < 64; kk += 32) {
      bf16x8 af[4], bfr[4];
#pragma unroll
      for (int m = 0; m < 4; ++m)
        af[m] = *(const bf16x8*)&As[wr * 64 + m * 16 + lrow][kk + lkb * 8];
#pragma unroll
      for (int n = 0; n < 4; ++n)
        bfr[n] = *(const bf16x8*)&Bs[wc * 64 + n * 16 + lrow][kk + lkb * 8];
#pragma unroll
      for (int m = 0; m < 4; ++m)
#pragma unroll
        for (int n = 0; n < 4; ++n)
          acc[m][n] = __builtin_amdgcn_mfma_f32_16x16x32_bf16(
              bfr[n], af[m], acc[m][n], 0, 0, 0);  // swapped operands
    }
    __syncthreads();
  }
  // i = i0 + wr*64 + m*16 + lrow ; d = wc*64 + n*16 + lkb*4 + r
#pragma unroll
  for (int m = 0; m < 4; ++m) {
    int gi = i0 + wr * 64 + m * 16 + lrow;
    float* orow = out + (size_t)gi * D_DIM;
#pragma unroll
    for (int n = 0; n < 4; ++n) {
      int d0 = wc * 64 + n * 16 + lkb * 4;
      f32x4 bv = *(const f32x4*)&bias[d0];
      f32x4 o;
#pragma unroll
      for (int r = 0; r < 4; ++r) o[r] = tanhf(acc[m][n][r] + bv[r]);
      *(f32x4*)&orow[d0] = o;  // workspace, 16B aligned
    }
  }
}

// ---- dist GEMM: LDS-free direct-global fragments, j-chunked writes -------
// dist[i][j] = sqrt(max(sq_i+sq_j-2*dot,0)) at F[5 + i*8192 + j], diag = 0.
// Block = 128 rows x 512 cols (4 sequential 128x128 subtiles). Grid 1024
// (64 ti x 16 jc), 4 blocks/CU x 4 waves for TLP. No LDS, no barriers:
// each lane loads its MFMA fragments straight from global (xbf is
// L2-resident, 16B-aligned, each wave-load = 16 fully-consumed 64B lines).
// Sequential adjacent subtiles make the shared 256B writeback units at
// segment seams merge in the same XCD's L2 (the round-1..6 1.63x write
// amplification came from cross-XCD unmerged seams + offset-20 partials).
// acc[m][n][r] = C[i][j]: i = i0+wr*64+m*16+lrow ; j = j0+wc*64+n*16+lkb*4+r
__global__ __launch_bounds__(256, 4) void dist_kernel(
    const unsigned short* __restrict__ xbf, const float* __restrict__ sqv,
    float* __restrict__ F) {
  int tid = threadIdx.x;
  int w = tid >> 6, lane = tid & 63;
  int wr = w >> 1, wc = w & 1;
  int lrow = lane & 15, lkb = lane >> 4;

  int b = blockIdx.x;
  int ti = b >> 4, jc = b & 15;
  int i0 = ti * 128;

  // A fragment base: row (i0 + wr*64 + m*16 + lrow), 16B chunk at k = t*32 + lkb*8
  const unsigned short* abase =
      xbf + (size_t)(i0 + wr * 64 + lrow) * L_DIM + lkb * 8;

#pragma unroll 1
  for (int js = 0; js < 4; ++js) {
    int j0 = jc * 512 + js * 128;
    const unsigned short* bbase =
        xbf + (size_t)(j0 + wc * 64 + lrow) * L_DIM + lkb * 8;

    f32x4 acc[4][4];
#pragma unroll
    for (int m = 0; m < 4; ++m)
#pragma unroll
      for (int n = 0; n < 4; ++n) acc[m][n] = (f32x4){0.f, 0.f, 0.f, 0.f};

    for (int t = 0; t < 12; ++t) {
      bf16x8 af[4], bfr[4];
#pragma unroll
      for (int m = 0; m < 4; ++m)
        af[m] = *(const bf16x8*)(abase + (size_t)m * 16 * L_DIM + t * 32);
#pragma unroll
      for (int n = 0; n < 4; ++n)
        bfr[n] = *(const bf16x8*)(bbase + (size_t)n * 16 * L_DIM + t * 32);
#pragma unroll
      for (int m = 0; m < 4; ++m)
#pragma unroll
        for (int n = 0; n < 4; ++n)
          acc[m][n] = __builtin_amdgcn_mfma_f32_16x16x32_bf16(
              bfr[n], af[m], acc[m][n], 0, 0, 0);  // swapped operands
    }

    // epilogue: per (m,n) one contiguous float4 store per lane
#pragma unroll
    for (int m = 0; m < 4; ++m) {
      int gi = i0 + wr * 64 + m * 16 + lrow;
      float si = sqv[gi];
      float* orow = F + 5 + (size_t)gi * N_INST;
#pragma unroll
      for (int n = 0; n < 4; ++n) {
        int gjb = j0 + wc * 64 + n * 16 + lkb * 4;
        f32x4 sj = *(const f32x4*)&sqv[gjb];
        f32x4u o;
#pragma unroll
        for (int r = 0; r < 4; ++r) {
          float d2 = si + sj[r] - 2.f * acc[m][n][r];
          float dv = (d2 > 0.f) ? sqrtf(d2) : 0.f;
          if (gi == gjb + r) dv = 0.f;
          o[r] = dv;
        }
        *(f32x4u*)&orow[gjb] = o;
      }
    }
  }
}

// ---- att logits -> exp, column sums --------------------------------------
__global__ __launch_bounds__(256) void attc_kernel(
    const float* __restrict__ h, const float* __restrict__ aW2,
    const float* __restrict__ ab2, float* __restrict__ exp_att,
    float* __restrict__ colsum) {
  __shared__ float csum[C_CLS];
  if (threadIdx.x < C_CLS) csum[threadIdx.x] = 0.f;
  __syncthreads();
  int i = blockIdx.x * 256 + threadIdx.x;  // 8192 rows
  float a[C_CLS];
#pragma unroll
  for (int c = 0; c < C_CLS; ++c) a[c] = ab2[c];
  const float* hr = h + (size_t)i * D_DIM;
  for (int d = 0; d < D_DIM; ++d) {
    float hv = hr[d];
#pragma unroll
    for (int c = 0; c < C_CLS; ++c) a[c] = fmaf(hv, aW2[d * C_CLS + c], a[c]);
  }
#pragma unroll
  for (int c = 0; c < C_CLS; ++c) {
    float e = expf(a[c]);
    exp_att[(size_t)i * C_CLS + c] = e;
    atomicAdd(&csum[c], e);
  }
  __syncthreads();
  if (threadIdx.x < C_CLS) atomicAdd(&colsum[threadIdx.x], csum[threadIdx.x]);
}

// ---- bagU[c][l] = sum_i exp_att[i][c] * x[i][l] --------------------------
__global__ __launch_bounds__(256) void bag_kernel(
    const float* __restrict__ x, const float* __restrict__ exp_att,
    float* __restrict__ bagU) {
  int t = threadIdx.x;
  int rbase = blockIdx.x * 32;
  float acc0[C_CLS] = {0, 0, 0, 0, 0}, acc1[C_CLS] = {0, 0, 0, 0, 0};
  int l0 = t, l1 = t + 256;  // l1 valid when t < 128
  for (int i = rbase; i < rbase + 32; ++i) {
    const float* xr = x + (size_t)i * L_DIM;
    float e[C_CLS];
#pragma unroll
    for (int c = 0; c < C_CLS; ++c) e[c] = exp_att[(size_t)i * C_CLS + c];
    float x0 = xr[l0];
#pragma unroll
    for (int c = 0; c < C_CLS; ++c) acc0[c] = fmaf(e[c], x0, acc0[c]);
    if (t < 128) {
      float x1 = xr[l1];
#pragma unroll
      for (int c = 0; c < C_CLS; ++c) acc1[c] = fmaf(e[c], x1, acc1[c]);
    }
  }
#pragma unroll
  for (int c = 0; c < C_CLS; ++c) atomicAdd(&bagU[c * L_DIM + l0], acc0[c]);
  if (t < 128)
#pragma unroll
    for (int c = 0; c < C_CLS; ++c) atomicAdd(&bagU[c * L_DIM + l1], acc1[c]);
}

// ---- final: normalize bag, per-class MLP head, write pred[0..4] ----------
__global__ __launch_bounds__(256) void final_kernel(
    const float* __restrict__ bagU, const float* __restrict__ colsum,
    const float* __restrict__ cW1, const float* __restrict__ cb1,
    const float* __restrict__ cW2, const float* __restrict__ cb2,
    float* __restrict__ out) {
  __shared__ float bag_s[C_CLS * L_DIM];
  __shared__ float h_s[C_CLS * 64];
  int t = threadIdx.x;
  for (int idx = t; idx < C_CLS * L_DIM; idx += 256) {
    int c = idx / L_DIM;
    bag_s[idx] = bagU[idx] / colsum[c];
  }
  __syncthreads();
  for (int idx = t; idx < C_CLS * 64; idx += 256) {
    int c = idx >> 6, hh = idx & 63;
    float acc = cb1[idx];
    for (int l = 0; l < L_DIM; ++l)
      acc = fmaf(bag_s[c * L_DIM + l], cW1[(size_t)(c * L_DIM + l) * 64 + hh], acc);
    h_s[idx] = fmaxf(acc, 0.f) * cW2[idx];
  }
  __syncthreads();
  if (t < C_CLS) {
    float p = cb2[t];
    for (int hh = 0; hh < 64; ++hh) p += h_s[t * 64 + hh];
    out[t] = p;
  }
}

extern "C" void kernel_launch(void* const* d_in, const int* in_sizes, int n_in,
                              void* d_out, int out_size, void* d_ws,
                              size_t ws_size, hipStream_t stream) {
  const float* x   = (const float*)d_in[0];
  const float* aW1 = (const float*)d_in[1];
  const float* ab1 = (const float*)d_in[2];
  const float* aW2 = (const float*)d_in[3];
  const float* ab2 = (const float*)d_in[4];
  const float* cW1 = (const float*)d_in[5];
  const float* cb1 = (const float*)d_in[6];
  const float* cW2 = (const float*)d_in[7];
  const float* cb2 = (const float*)d_in[8];
  float* outp = (float*)d_out;

  char* ws = (char*)d_ws;
  unsigned short* xbf = (unsigned short*)(ws);              // 6,291,456
  unsigned short* w1t = (unsigned short*)(ws + 6291456);    //    98,304
  float* sq           = (float*)(ws + 6389760);             //    32,768
  float* h_tanh       = (float*)(ws + 6422528);             // 4,194,304
  float* exp_att      = (float*)(ws + 10616832);            //   163,840
  float* colsum       = (float*)(ws + 10780672);            //        64
  float* bagU         = (float*)(ws + 10780736);            //     7,680

  hipMemsetAsync(ws + 10780672, 0, 64 + C_CLS * L_DIM * 4, stream);

  prep_x_kernel<<<2048, 256, 0, stream>>>(x, xbf, sq);
  prep_w_kernel<<<192, 256, 0, stream>>>(aW1, w1t);
  attn_gemm_kernel<<<64, 256, 0, stream>>>(xbf, w1t, ab1, h_tanh);
  attc_kernel<<<32, 256, 0, stream>>>(h_tanh, aW2, ab2, exp_att, colsum);
  bag_kernel<<<256, 256, 0, stream>>>(x, exp_att, bagU);
  final_kernel<<<1, 256, 0, stream>>>(bagU, colsum, cW1, cb1, cW2, cb2, outp);
  dist_kernel<<<1024, 256, 0, stream>>>(xbf, sq, outp);
}

// Round 8
// 333.196 us; speedup vs baseline: 1.5893x; 1.5893x over previous
//
#include <hip/hip_runtime.h>
#include <cstdint>
#include <cstddef>

#define N_INST 8192
#define L_DIM  384
#define D_DIM  128
#define C_CLS  5

typedef __bf16 bf16x8 __attribute__((ext_vector_type(8)));
typedef float  f32x4  __attribute__((ext_vector_type(4)));
// 4-byte-aligned float4 for the dist output (base offset 20 B).
typedef float  f32x4u __attribute__((ext_vector_type(4), aligned(4)));

typedef __attribute__((address_space(1))) void gvoid_t;
typedef __attribute__((address_space(3))) void lvoid_t;

__device__ __forceinline__ unsigned short f2bf(float f) {
  unsigned u = __float_as_uint(f);
  unsigned r = (u + 0x7FFFu + ((u >> 16) & 1u)) >> 16;  // RNE
  return (unsigned short)r;
}
__device__ __forceinline__ float bf2f(unsigned short b) {
  return __uint_as_float(((unsigned)b) << 16);
}

__device__ __forceinline__ void gload_lds16(const void* g, void* lds) {
  __builtin_amdgcn_global_load_lds(
      (gvoid_t*)(uintptr_t)g,
      (lvoid_t*)(uint32_t)(uintptr_t)lds,
      16, 0, 0);
}

// ---- prep: x -> bf16, sq[i] = sum(bf16(x_i)^2) in fp32 -------------------
__global__ __launch_bounds__(256) void prep_x_kernel(
    const float* __restrict__ x, unsigned short* __restrict__ xbf,
    float* __restrict__ sq) {
  int w = threadIdx.x >> 6, lane = threadIdx.x & 63;
  int row = blockIdx.x * 4 + w;
  const float* xr = x + (size_t)row * L_DIM;
  unsigned short* br = xbf + (size_t)row * L_DIM;
  float s = 0.f;
#pragma unroll
  for (int k = 0; k < 6; ++k) {
    float v = xr[lane + 64 * k];
    unsigned short b = f2bf(v);
    br[lane + 64 * k] = b;
    float vb = bf2f(b);
    s = fmaf(vb, vb, s);
  }
#pragma unroll
  for (int off = 32; off; off >>= 1) s += __shfl_down(s, off, 64);
  if (lane == 0) sq[row] = s;
}

// ---- prep: aW1 [384][128] -> aW1T_bf [128][384] --------------------------
__global__ __launch_bounds__(256) void prep_w_kernel(
    const float* __restrict__ aW1, unsigned short* __restrict__ w1t) {
  int idx = blockIdx.x * 256 + threadIdx.x;  // 49152 total
  int d = idx / L_DIM, l = idx - d * L_DIM;
  w1t[idx] = f2bf(aW1[(size_t)l * D_DIM + d]);
}

// ---- attention GEMM: h_tanh[i][d] = tanh(x_bf . aW1T[d] + ab1[d]) --------
__global__ __launch_bounds__(256, 2) void attn_gemm_kernel(
    const unsigned short* __restrict__ amat,   // x_bf [8192][384]
    const unsigned short* __restrict__ bmat,   // aW1T_bf [128][384]
    const float* __restrict__ bias,            // ab1
    float* __restrict__ out) {
  __shared__ alignas(16) unsigned short As[128][64];
  __shared__ alignas(16) unsigned short Bs[128][64];

  int tid = threadIdx.x;
  int w = tid >> 6, lane = tid & 63;
  int wr = w >> 1, wc = w & 1;
  int i0 = blockIdx.x * 128;

  const unsigned short* asrc = amat + (size_t)i0 * L_DIM;
  const unsigned short* bsrc = bmat;

  f32x4 acc[4][4];
#pragma unroll
  for (int m = 0; m < 4; ++m)
#pragma unroll
    for (int n = 0; n < 4; ++n) acc[m][n] = (f32x4){0.f, 0.f, 0.f, 0.f};

  int lrow = lane & 15, lkb = lane >> 4;

  for (int kc = 0; kc < 6; ++kc) {
    int k0 = kc * 64;
#pragma unroll
    for (int c = 0; c < 4; ++c) {
      int rb = c * 32 + w * 8;
      gload_lds16(asrc + (size_t)(rb + (lane >> 3)) * L_DIM + k0 + (lane & 7) * 8,
                  &As[rb][0]);
      gload_lds16(bsrc + (size_t)(rb + (lane >> 3)) * L_DIM + k0 + (lane & 7) * 8,
                  &Bs[rb][0]);
    }
    __syncthreads();
#pragma unroll
    for (int kk = 0; kk < 64; kk += 32) {
      bf16x8 af[4], bfr[4];
#pragma unroll
      for (int m = 0; m < 4; ++m)
        af[m] = *(const bf16x8*)&As[wr * 64 + m * 16 + lrow][kk + lkb * 8];
#pragma unroll
      for (int n = 0; n < 4; ++n)
        bfr[n] = *(const bf16x8*)&Bs[wc * 64 + n * 16 + lrow][kk + lkb * 8];
#pragma unroll
      for (int m = 0; m < 4; ++m)
#pragma unroll
        for (int n = 0; n < 4; ++n)
          acc[m][n] = __builtin_amdgcn_mfma_f32_16x16x32_bf16(
              bfr[n], af[m], acc[m][n], 0, 0, 0);  // swapped operands
    }
    __syncthreads();
  }
  // i = i0 + wr*64 + m*16 + lrow ; d = wc*64 + n*16 + lkb*4 + r
#pragma unroll
  for (int m = 0; m < 4; ++m) {
    int gi = i0 + wr * 64 + m * 16 + lrow;
    float* orow = out + (size_t)gi * D_DIM;
#pragma unroll
    for (int n = 0; n < 4; ++n) {
      int d0 = wc * 64 + n * 16 + lkb * 4;
      f32x4 bv = *(const f32x4*)&bias[d0];
      f32x4 o;
#pragma unroll
      for (int r = 0; r < 4; ++r) o[r] = tanhf(acc[m][n][r] + bv[r]);
      *(f32x4*)&orow[d0] = o;  // workspace, 16B aligned
    }
  }
}

// ---- dist GEMM: row-strip kernel, sequential writes ----------------------
// dist[i][j] = sqrt(max(sq_i+sq_j-2*dot,0)) at F[5 + i*8192 + j], diag = 0.
// 256 blocks (1/CU), block owns rows [bid*32, +32), sweeps all 8192 cols in
// 128 j-windows of 64. Per row the writes advance strictly left-to-right
// (256 B per window) -> L2 write-combines into sequential streams; the
// offset-20 partial-granule seams merge between adjacent windows of the
// SAME block (the round 1-7 1.6-2.2x write amplification came from
// cross-XCD tile seams + row-interleaved 64B pieces).
// A strip (32 rows x 384 k) lives in registers (96 VGPR, replicated per
// wave). B window staged in WAVE-PRIVATE double-buffered LDS via
// global_load_lds: wave w stages+reads only cols [w*16,+16) -> no barriers
// in the loop; one s_waitcnt vmcnt(0) per step (before stores) is the only
// sync. sq[] staged to LDS once so the per-step sj read is lgkm, not vmcnt.
// LDS: Bs 2*64*384*2 = 96 KB + sq 32 KB = 128 KB.
// Bank swizzle on Bs (768 B rows = 32-way conflict otherwise): phys 16B
// chunk s of row r holds global chunk s ^ (r&7); staged via pre-swizzled
// per-lane global source (linear LDS dest), read back with the same XOR.
__global__ __launch_bounds__(256) void dist_kernel(
    const unsigned short* __restrict__ xbf, const float* __restrict__ sqv,
    float* __restrict__ F) {
  __shared__ alignas(16) unsigned short Bs[2][64][L_DIM];
  __shared__ alignas(16) float sq_lds[N_INST];

  int tid = threadIdx.x;
  int w = tid >> 6, lane = tid & 63;
  int lrow = lane & 15, lkb = lane >> 4;
  int rowbase = blockIdx.x * 32;

  // ---- A strip into registers: rows rowbase + m*16 + lrow, all K -------
  bf16x8 a_reg[2][12];
#pragma unroll
  for (int m = 0; m < 2; ++m)
#pragma unroll
    for (int t = 0; t < 12; ++t)
      a_reg[m][t] = *(const bf16x8*)(
          xbf + (size_t)(rowbase + m * 16 + lrow) * L_DIM + t * 32 + lkb * 8);

  float si0 = sqv[rowbase + lrow];
  float si1 = sqv[rowbase + 16 + lrow];

  // ---- stage sq[0..8192) into LDS (8 rounds x 1KB per wave) ------------
#pragma unroll
  for (int q = 0; q < 8; ++q)
    gload_lds16((const char*)sqv + w * 8192 + q * 1024 + lane * 16,
                (char*)sq_lds + w * 8192 + q * 1024);

  // ---- per-lane staging source map (12 rounds x 1KB cover 16x768B) -----
  int srow_q[12], soff_q[12];
#pragma unroll
  for (int q = 0; q < 12; ++q) {
    int o = q * 1024 + lane * 16;
    int sr = o / 768;
    int c16 = (o - sr * 768) >> 4;
    srow_q[q] = sr;
    soff_q[q] = (c16 ^ (sr & 7)) << 3;  // element offset in row (swizzled)
  }

#define STAGE(buf, js)                                                      \
  {                                                                         \
    const unsigned short* bsrc = xbf + (size_t)((js)*64 + w * 16) * L_DIM;  \
    char* ldst = (char*)&Bs[buf][w * 16][0];                                \
    _Pragma("unroll") for (int q = 0; q < 12; ++q)                          \
        gload_lds16(bsrc + (size_t)srow_q[q] * L_DIM + soff_q[q],           \
                    ldst + q * 1024);                                       \
  }

  STAGE(0, 0);
  __syncthreads();  // drains sq + first stage; only barrier in the kernel

  int sw = lrow & 7;
#pragma unroll 1
  for (int js = 0; js < 128; ++js) {
    int p = js & 1;
    int gjb = js * 64 + w * 16 + lkb * 4;
    f32x4 sj = *(const f32x4*)&sq_lds[gjb];  // LDS read: lgkm domain
    if (js < 127) STAGE(p ^ 1, js + 1);      // prefetch next window

    f32x4 acc0 = (f32x4){0.f, 0.f, 0.f, 0.f};
    f32x4 acc1 = (f32x4){0.f, 0.f, 0.f, 0.f};
    const unsigned short* brow = &Bs[p][w * 16 + lrow][0];
#pragma unroll
    for (int t = 0; t < 12; ++t) {
      bf16x8 bfr = *(const bf16x8*)(brow + ((((t << 2) | lkb) ^ sw) << 3));
      acc0 = __builtin_amdgcn_mfma_f32_16x16x32_bf16(bfr, a_reg[0][t], acc0,
                                                     0, 0, 0);
      acc1 = __builtin_amdgcn_mfma_f32_16x16x32_bf16(bfr, a_reg[1][t], acc1,
                                                     0, 0, 0);
    }

    // epilogue values in regs before the wait
    f32x4u o0, o1;
#pragma unroll
    for (int r = 0; r < 4; ++r) {
      float d2 = si0 + sj[r] - 2.f * acc0[r];
      float dv = (d2 > 0.f) ? sqrtf(d2) : 0.f;
      if (rowbase + lrow == gjb + r) dv = 0.f;
      o0[r] = dv;
      d2 = si1 + sj[r] - 2.f * acc1[r];
      dv = (d2 > 0.f) ? sqrtf(d2) : 0.f;
      if (rowbase + 16 + lrow == gjb + r) dv = 0.f;
      o1[r] = dv;
    }

    // drain this step's prefetch (and last step's stores, long since done)
    asm volatile("s_waitcnt vmcnt(0)" ::: "memory");
    __builtin_amdgcn_sched_barrier(0);

    *(f32x4u*)(F + 5 + (size_t)(rowbase + lrow) * N_INST + gjb) = o0;
    *(f32x4u*)(F + 5 + (size_t)(rowbase + 16 + lrow) * N_INST + gjb) = o1;
  }
#undef STAGE
}

// ---- att logits -> exp, column sums --------------------------------------
__global__ __launch_bounds__(256) void attc_kernel(
    const float* __restrict__ h, const float* __restrict__ aW2,
    const float* __restrict__ ab2, float* __restrict__ exp_att,
    float* __restrict__ colsum) {
  __shared__ float csum[C_CLS];
  if (threadIdx.x < C_CLS) csum[threadIdx.x] = 0.f;
  __syncthreads();
  int i = blockIdx.x * 256 + threadIdx.x;  // 8192 rows
  float a[C_CLS];
#pragma unroll
  for (int c = 0; c < C_CLS; ++c) a[c] = ab2[c];
  const float* hr = h + (size_t)i * D_DIM;
  for (int d = 0; d < D_DIM; ++d) {
    float hv = hr[d];
#pragma unroll
    for (int c = 0; c < C_CLS; ++c) a[c] = fmaf(hv, aW2[d * C_CLS + c], a[c]);
  }
#pragma unroll
  for (int c = 0; c < C_CLS; ++c) {
    float e = expf(a[c]);
    exp_att[(size_t)i * C_CLS + c] = e;
    atomicAdd(&csum[c], e);
  }
  __syncthreads();
  if (threadIdx.x < C_CLS) atomicAdd(&colsum[threadIdx.x], csum[threadIdx.x]);
}

// ---- bagU[c][l] = sum_i exp_att[i][c] * x[i][l] --------------------------
__global__ __launch_bounds__(256) void bag_kernel(
    const float* __restrict__ x, const float* __restrict__ exp_att,
    float* __restrict__ bagU) {
  int t = threadIdx.x;
  int rbase = blockIdx.x * 32;
  float acc0[C_CLS] = {0, 0, 0, 0, 0}, acc1[C_CLS] = {0, 0, 0, 0, 0};
  int l0 = t, l1 = t + 256;  // l1 valid when t < 128
  for (int i = rbase; i < rbase + 32; ++i) {
    const float* xr = x + (size_t)i * L_DIM;
    float e[C_CLS];
#pragma unroll
    for (int c = 0; c < C_CLS; ++c) e[c] = exp_att[(size_t)i * C_CLS + c];
    float x0 = xr[l0];
#pragma unroll
    for (int c = 0; c < C_CLS; ++c) acc0[c] = fmaf(e[c], x0, acc0[c]);
    if (t < 128) {
      float x1 = xr[l1];
#pragma unroll
      for (int c = 0; c < C_CLS; ++c) acc1[c] = fmaf(e[c], x1, acc1[c]);
    }
  }
#pragma unroll
  for (int c = 0; c < C_CLS; ++c) atomicAdd(&bagU[c * L_DIM + l0], acc0[c]);
  if (t < 128)
#pragma unroll
    for (int c = 0; c < C_CLS; ++c) atomicAdd(&bagU[c * L_DIM + l1], acc1[c]);
}

// ---- final: normalize bag, per-class MLP head, write pred[0..4] ----------
__global__ __launch_bounds__(256) void final_kernel(
    const float* __restrict__ bagU, const float* __restrict__ colsum,
    const float* __restrict__ cW1, const float* __restrict__ cb1,
    const float* __restrict__ cW2, const float* __restrict__ cb2,
    float* __restrict__ out) {
  __shared__ float bag_s[C_CLS * L_DIM];
  __shared__ float h_s[C_CLS * 64];
  int t = threadIdx.x;
  for (int idx = t; idx < C_CLS * L_DIM; idx += 256) {
    int c = idx / L_DIM;
    bag_s[idx] = bagU[idx] / colsum[c];
  }
  __syncthreads();
  for (int idx = t; idx < C_CLS * 64; idx += 256) {
    int c = idx >> 6, hh = idx & 63;
    float acc = cb1[idx];
    for (int l = 0; l < L_DIM; ++l)
      acc = fmaf(bag_s[c * L_DIM + l], cW1[(size_t)(c * L_DIM + l) * 64 + hh], acc);
    h_s[idx] = fmaxf(acc, 0.f) * cW2[idx];
  }
  __syncthreads();
  if (t < C_CLS) {
    float p = cb2[t];
    for (int hh = 0; hh < 64; ++hh) p += h_s[t * 64 + hh];
    out[t] = p;
  }
}

extern "C" void kernel_launch(void* const* d_in, const int* in_sizes, int n_in,
                              void* d_out, int out_size, void* d_ws,
                              size_t ws_size, hipStream_t stream) {
  const float* x   = (const float*)d_in[0];
  const float* aW1 = (const float*)d_in[1];
  const float* ab1 = (const float*)d_in[2];
  const float* aW2 = (const float*)d_in[3];
  const float* ab2 = (const float*)d_in[4];
  const float* cW1 = (const float*)d_in[5];
  const float* cb1 = (const float*)d_in[6];
  const float* cW2 = (const float*)d_in[7];
  const float* cb2 = (const float*)d_in[8];
  float* outp = (float*)d_out;

  char* ws = (char*)d_ws;
  unsigned short* xbf = (unsigned short*)(ws);              // 6,291,456
  unsigned short* w1t = (unsigned short*)(ws + 6291456);    //    98,304
  float* sq           = (float*)(ws + 6389760);             //    32,768
  float* h_tanh       = (float*)(ws + 6422528);             // 4,194,304
  float* exp_att      = (float*)(ws + 10616832);            //   163,840
  float* colsum       = (float*)(ws + 10780672);            //        64
  float* bagU         = (float*)(ws + 10780736);            //     7,680

  hipMemsetAsync(ws + 10780672, 0, 64 + C_CLS * L_DIM * 4, stream);

  prep_x_kernel<<<2048, 256, 0, stream>>>(x, xbf, sq);
  prep_w_kernel<<<192, 256, 0, stream>>>(aW1, w1t);
  attn_gemm_kernel<<<64, 256, 0, stream>>>(xbf, w1t, ab1, h_tanh);
  attc_kernel<<<32, 256, 0, stream>>>(h_tanh, aW2, ab2, exp_att, colsum);
  bag_kernel<<<256, 256, 0, stream>>>(x, exp_att, bagU);
  final_kernel<<<1, 256, 0, stream>>>(bagU, colsum, cW1, cb1, cW2, cb2, outp);
  dist_kernel<<<256, 256, 0, stream>>>(xbf, sq, outp);
}

// Round 9
// 191.065 us; speedup vs baseline: 2.7715x; 1.7439x over previous
//
#include <hip/hip_runtime.h>
#include <cstdint>
#include <cstddef>

#define N_INST 8192
#define L_DIM  384
#define D_DIM  128
#define C_CLS  5

typedef __bf16 bf16x8 __attribute__((ext_vector_type(8)));
typedef float  f32x4  __attribute__((ext_vector_type(4)));
typedef float  f32x4u __attribute__((ext_vector_type(4), aligned(4)));

typedef __attribute__((address_space(1))) void gvoid_t;
typedef __attribute__((address_space(3))) void lvoid_t;

__device__ __forceinline__ unsigned short f2bf(float f) {
  unsigned u = __float_as_uint(f);
  unsigned r = (u + 0x7FFFu + ((u >> 16) & 1u)) >> 16;  // RNE
  return (unsigned short)r;
}
__device__ __forceinline__ float bf2f(unsigned short b) {
  return __uint_as_float(((unsigned)b) << 16);
}

__device__ __forceinline__ void gload_lds16(const void* g, void* lds) {
  __builtin_amdgcn_global_load_lds(
      (gvoid_t*)(uintptr_t)g,
      (lvoid_t*)(uint32_t)(uintptr_t)lds,
      16, 0, 0);
}

// ---- prep: x -> bf16, sq[i] = sum(bf16(x_i)^2) in fp32 -------------------
__global__ __launch_bounds__(256) void prep_x_kernel(
    const float* __restrict__ x, unsigned short* __restrict__ xbf,
    float* __restrict__ sq) {
  int w = threadIdx.x >> 6, lane = threadIdx.x & 63;
  int row = blockIdx.x * 4 + w;
  const float* xr = x + (size_t)row * L_DIM;
  unsigned short* br = xbf + (size_t)row * L_DIM;
  float s = 0.f;
#pragma unroll
  for (int k = 0; k < 6; ++k) {
    float v = xr[lane + 64 * k];
    unsigned short b = f2bf(v);
    br[lane + 64 * k] = b;
    float vb = bf2f(b);
    s = fmaf(vb, vb, s);
  }
#pragma unroll
  for (int off = 32; off; off >>= 1) s += __shfl_down(s, off, 64);
  if (lane == 0) sq[row] = s;
}

// ---- prep: aW1 [384][128] -> aW1T_bf [128][384] --------------------------
__global__ __launch_bounds__(256) void prep_w_kernel(
    const float* __restrict__ aW1, unsigned short* __restrict__ w1t) {
  int idx = blockIdx.x * 256 + threadIdx.x;  // 49152 total
  int d = idx / L_DIM, l = idx - d * L_DIM;
  w1t[idx] = f2bf(aW1[(size_t)l * D_DIM + d]);
}

// ---- attention GEMM: h_tanh[i][d] = tanh(x_bf . aW1T[d] + ab1[d]) --------
__global__ __launch_bounds__(256, 2) void attn_gemm_kernel(
    const unsigned short* __restrict__ amat,   // x_bf [8192][384]
    const unsigned short* __restrict__ bmat,   // aW1T_bf [128][384]
    const float* __restrict__ bias,            // ab1
    float* __restrict__ out) {
  __shared__ alignas(16) unsigned short As[128][64];
  __shared__ alignas(16) unsigned short Bs[128][64];

  int tid = threadIdx.x;
  int w = tid >> 6, lane = tid & 63;
  int wr = w >> 1, wc = w & 1;
  int i0 = blockIdx.x * 128;

  const unsigned short* asrc = amat + (size_t)i0 * L_DIM;
  const unsigned short* bsrc = bmat;

  f32x4 acc[4][4];
#pragma unroll
  for (int m = 0; m < 4; ++m)
#pragma unroll
    for (int n = 0; n < 4; ++n) acc[m][n] = (f32x4){0.f, 0.f, 0.f, 0.f};

  int lrow = lane & 15, lkb = lane >> 4;

  for (int kc = 0; kc < 6; ++kc) {
    int k0 = kc * 64;
#pragma unroll
    for (int c = 0; c < 4; ++c) {
      int rb = c * 32 + w * 8;
      gload_lds16(asrc + (size_t)(rb + (lane >> 3)) * L_DIM + k0 + (lane & 7) * 8,
                  &As[rb][0]);
      gload_lds16(bsrc + (size_t)(rb + (lane >> 3)) * L_DIM + k0 + (lane & 7) * 8,
                  &Bs[rb][0]);
    }
    __syncthreads();
#pragma unroll
    for (int kk = 0; kk < 64; kk += 32) {
      bf16x8 af[4], bfr[4];
#pragma unroll
      for (int m = 0; m < 4; ++m)
        af[m] = *(const bf16x8*)&As[wr * 64 + m * 16 + lrow][kk + lkb * 8];
#pragma unroll
      for (int n = 0; n < 4; ++n)
        bfr[n] = *(const bf16x8*)&Bs[wc * 64 + n * 16 + lrow][kk + lkb * 8];
#pragma unroll
      for (int m = 0; m < 4; ++m)
#pragma unroll
        for (int n = 0; n < 4; ++n)
          acc[m][n] = __builtin_amdgcn_mfma_f32_16x16x32_bf16(
              bfr[n], af[m], acc[m][n], 0, 0, 0);  // swapped operands
    }
    __syncthreads();
  }
  // i = i0 + wr*64 + m*16 + lrow ; d = wc*64 + n*16 + lkb*4 + r
#pragma unroll
  for (int m = 0; m < 4; ++m) {
    int gi = i0 + wr * 64 + m * 16 + lrow;
    float* orow = out + (size_t)gi * D_DIM;
#pragma unroll
    for (int n = 0; n < 4; ++n) {
      int d0 = wc * 64 + n * 16 + lkb * 4;
      f32x4 bv = *(const f32x4*)&bias[d0];
      f32x4 o;
#pragma unroll
      for (int r = 0; r < 4; ++r) o[r] = tanhf(acc[m][n][r] + bv[r]);
      *(f32x4*)&orow[d0] = o;  // workspace, 16B aligned
    }
  }
}

// ---- head: dist cols j=0,1,2 for all rows (unaligned leftovers) ----------
__global__ __launch_bounds__(256) void head_kernel(
    const unsigned short* __restrict__ xbf, const float* __restrict__ sqv,
    float* __restrict__ F) {
  int w = threadIdx.x >> 6, lane = threadIdx.x & 63;
  int i = blockIdx.x * 4 + w;
  float a0 = 0.f, a1 = 0.f, a2 = 0.f;
  if (lane < 48) {
    const unsigned short* xi = xbf + (size_t)i * L_DIM + lane * 8;
    const unsigned short* x0 = xbf + lane * 8;
    const unsigned short* x1 = xbf + L_DIM + lane * 8;
    const unsigned short* x2 = xbf + 2 * L_DIM + lane * 8;
#pragma unroll
    for (int e = 0; e < 8; ++e) {
      float v = bf2f(xi[e]);
      a0 = fmaf(v, bf2f(x0[e]), a0);
      a1 = fmaf(v, bf2f(x1[e]), a1);
      a2 = fmaf(v, bf2f(x2[e]), a2);
    }
  }
#pragma unroll
  for (int off = 32; off; off >>= 1) {
    a0 += __shfl_down(a0, off, 64);
    a1 += __shfl_down(a1, off, 64);
    a2 += __shfl_down(a2, off, 64);
  }
  if (lane == 0) {
    float si = sqv[i];
    float dots[3] = {a0, a1, a2};
#pragma unroll
    for (int j = 0; j < 3; ++j) {
      float d2 = si + sqv[j] - 2.f * dots[j];
      float dv = (d2 > 0.f) ? sqrtf(d2) : 0.f;
      if (i == j) dv = 0.f;
      F[5 + (size_t)i * N_INST + j] = dv;
    }
  }
}

// ---- dist GEMM: phase-shifted windows for 32B-sector-aligned stores ------
// dist[i][j] at F[5 + i*8192 + j]; the +5 prefix puts j=0 at byte 20 mod 32,
// so j-aligned stores leave partial 32B sectors everywhere (R1/R2/R8 all
// measured WRITE_SIZE ~1.67x ideal regardless of pattern). Fix: block
// (ti,tj) computes/writes the SHIFTED window j in [tj*128+3, +128) — since
// (5+3) % 8 == 0, every f32x4 store is 16B-aligned and lane pairs complete
// full 32B sectors within one instruction. Windows tile [3,8192); j<3 done
// by head_kernel; the one vector crossing j=8192 masks to a scalar.
// Implementation: just shift the B operand base by +3 rows.
// acc[m][n][r] = dot(i, j): i = i0+wr*64+m*16+lrow ;
//                           j = j0+3+wc*64+n*16+lkb*4+r
// LDS XOR-swizzle (T2, from R5) retained: stage with pre-swizzled global
// source (linear LDS dest), read back with matching XOR.
__global__ __launch_bounds__(256, 2) void dist_kernel(
    const unsigned short* __restrict__ xbf, const float* __restrict__ sqv,
    float* __restrict__ F) {
  __shared__ alignas(16) unsigned short As[128][64];
  __shared__ alignas(16) unsigned short Bs[128][64];

  int tid = threadIdx.x;
  int w = tid >> 6, lane = tid & 63;
  int wr = w >> 1, wc = w & 1;

  int b = blockIdx.x;
  int ti = b >> 6, tj = b & 63;
  int i0 = ti * 128, j0 = tj * 128;

  const unsigned short* asrc = xbf + (size_t)i0 * L_DIM;
  const unsigned short* bsrc = xbf + (size_t)(j0 + 3) * L_DIM;  // shifted

  f32x4 acc[4][4];
#pragma unroll
  for (int m = 0; m < 4; ++m)
#pragma unroll
    for (int n = 0; n < 4; ++n) acc[m][n] = (f32x4){0.f, 0.f, 0.f, 0.f};

  int lrow = lane & 15, lkb = lane >> 4;
  int schunk = ((lane & 7) ^ (lane >> 3)) * 8;  // pre-swizzled source chunk
  int swz = (lane & 7) << 3;                    // read-side xor

  for (int kc = 0; kc < 6; ++kc) {
    int k0 = kc * 64;
#pragma unroll
    for (int c = 0; c < 4; ++c) {
      int rb = c * 32 + w * 8;  // wave-uniform LDS base row (rb % 8 == 0)
      gload_lds16(asrc + (size_t)(rb + (lane >> 3)) * L_DIM + k0 + schunk,
                  &As[rb][0]);
      gload_lds16(bsrc + (size_t)(rb + (lane >> 3)) * L_DIM + k0 + schunk,
                  &Bs[rb][0]);
    }
    __syncthreads();
#pragma unroll
    for (int kk = 0; kk < 64; kk += 32) {
      bf16x8 af[4], bfr[4];
#pragma unroll
      for (int m = 0; m < 4; ++m)
        af[m] = *(const bf16x8*)&As[wr * 64 + m * 16 + lrow][(kk + lkb * 8) ^ swz];
#pragma unroll
      for (int n = 0; n < 4; ++n)
        bfr[n] = *(const bf16x8*)&Bs[wc * 64 + n * 16 + lrow][(kk + lkb * 8) ^ swz];
#pragma unroll
      for (int m = 0; m < 4; ++m)
#pragma unroll
        for (int n = 0; n < 4; ++n)
          acc[m][n] = __builtin_amdgcn_mfma_f32_16x16x32_bf16(
              bfr[n], af[m], acc[m][n], 0, 0, 0);  // swapped operands
    }
    __syncthreads();
  }

  // epilogue: 16B-aligned f32x4 stores (element index ≡ 0 mod 4)
#pragma unroll
  for (int m = 0; m < 4; ++m) {
    int gi = i0 + wr * 64 + m * 16 + lrow;
    float si = sqv[gi];
    float* orow = F + 5 + (size_t)gi * N_INST;
#pragma unroll
    for (int n = 0; n < 4; ++n) {
      int gjb = j0 + 3 + wc * 64 + n * 16 + lkb * 4;
      f32x4u sj = *(const f32x4u*)&sqv[gjb];  // 4B-aligned read (gjb%4==3)
      f32x4 o;
#pragma unroll
      for (int r = 0; r < 4; ++r) {
        float d2 = si + sj[r] - 2.f * acc[m][n][r];
        float dv = (d2 > 0.f) ? sqrtf(d2) : 0.f;
        if (gi == gjb + r) dv = 0.f;
        o[r] = dv;
      }
      if (gjb + 3 < N_INST) {
        *(f32x4*)&orow[gjb] = o;  // aligned: (5+gjb) % 4 == 0
      } else {
        orow[N_INST - 1] = o[0];  // gjb == 8191 (tj=63 edge), j=8191 only
      }
    }
  }
}

// ---- att logits -> exp, column sums --------------------------------------
__global__ __launch_bounds__(256) void attc_kernel(
    const float* __restrict__ h, const float* __restrict__ aW2,
    const float* __restrict__ ab2, float* __restrict__ exp_att,
    float* __restrict__ colsum) {
  __shared__ float csum[C_CLS];
  if (threadIdx.x < C_CLS) csum[threadIdx.x] = 0.f;
  __syncthreads();
  int i = blockIdx.x * 256 + threadIdx.x;  // 8192 rows
  float a[C_CLS];
#pragma unroll
  for (int c = 0; c < C_CLS; ++c) a[c] = ab2[c];
  const float* hr = h + (size_t)i * D_DIM;
  for (int d = 0; d < D_DIM; ++d) {
    float hv = hr[d];
#pragma unroll
    for (int c = 0; c < C_CLS; ++c) a[c] = fmaf(hv, aW2[d * C_CLS + c], a[c]);
  }
#pragma unroll
  for (int c = 0; c < C_CLS; ++c) {
    float e = expf(a[c]);
    exp_att[(size_t)i * C_CLS + c] = e;
    atomicAdd(&csum[c], e);
  }
  __syncthreads();
  if (threadIdx.x < C_CLS) atomicAdd(&colsum[threadIdx.x], csum[threadIdx.x]);
}

// ---- bagU[c][l] = sum_i exp_att[i][c] * x[i][l] --------------------------
__global__ __launch_bounds__(256) void bag_kernel(
    const float* __restrict__ x, const float* __restrict__ exp_att,
    float* __restrict__ bagU) {
  int t = threadIdx.x;
  int rbase = blockIdx.x * 32;
  float acc0[C_CLS] = {0, 0, 0, 0, 0}, acc1[C_CLS] = {0, 0, 0, 0, 0};
  int l0 = t, l1 = t + 256;  // l1 valid when t < 128
  for (int i = rbase; i < rbase + 32; ++i) {
    const float* xr = x + (size_t)i * L_DIM;
    float e[C_CLS];
#pragma unroll
    for (int c = 0; c < C_CLS; ++c) e[c] = exp_att[(size_t)i * C_CLS + c];
    float x0 = xr[l0];
#pragma unroll
    for (int c = 0; c < C_CLS; ++c) acc0[c] = fmaf(e[c], x0, acc0[c]);
    if (t < 128) {
      float x1 = xr[l1];
#pragma unroll
      for (int c = 0; c < C_CLS; ++c) acc1[c] = fmaf(e[c], x1, acc1[c]);
    }
  }
#pragma unroll
  for (int c = 0; c < C_CLS; ++c) atomicAdd(&bagU[c * L_DIM + l0], acc0[c]);
  if (t < 128)
#pragma unroll
    for (int c = 0; c < C_CLS; ++c) atomicAdd(&bagU[c * L_DIM + l1], acc1[c]);
}

// ---- final: normalize bag, per-class MLP head, write pred[0..4] ----------
__global__ __launch_bounds__(256) void final_kernel(
    const float* __restrict__ bagU, const float* __restrict__ colsum,
    const float* __restrict__ cW1, const float* __restrict__ cb1,
    const float* __restrict__ cW2, const float* __restrict__ cb2,
    float* __restrict__ out) {
  __shared__ float bag_s[C_CLS * L_DIM];
  __shared__ float h_s[C_CLS * 64];
  int t = threadIdx.x;
  for (int idx = t; idx < C_CLS * L_DIM; idx += 256) {
    int c = idx / L_DIM;
    bag_s[idx] = bagU[idx] / colsum[c];
  }
  __syncthreads();
  for (int idx = t; idx < C_CLS * 64; idx += 256) {
    int c = idx >> 6, hh = idx & 63;
    float acc = cb1[idx];
    for (int l = 0; l < L_DIM; ++l)
      acc = fmaf(bag_s[c * L_DIM + l], cW1[(size_t)(c * L_DIM + l) * 64 + hh], acc);
    h_s[idx] = fmaxf(acc, 0.f) * cW2[idx];
  }
  __syncthreads();
  if (t < C_CLS) {
    float p = cb2[t];
    for (int hh = 0; hh < 64; ++hh) p += h_s[t * 64 + hh];
    out[t] = p;
  }
}

extern "C" void kernel_launch(void* const* d_in, const int* in_sizes, int n_in,
                              void* d_out, int out_size, void* d_ws,
                              size_t ws_size, hipStream_t stream) {
  const float* x   = (const float*)d_in[0];
  const float* aW1 = (const float*)d_in[1];
  const float* ab1 = (const float*)d_in[2];
  const float* aW2 = (const float*)d_in[3];
  const float* ab2 = (const float*)d_in[4];
  const float* cW1 = (const float*)d_in[5];
  const float* cb1 = (const float*)d_in[6];
  const float* cW2 = (const float*)d_in[7];
  const float* cb2 = (const float*)d_in[8];
  float* outp = (float*)d_out;

  char* ws = (char*)d_ws;
  unsigned short* xbf = (unsigned short*)(ws);              // 6,291,456
  unsigned short* w1t = (unsigned short*)(ws + 6291456);    //    98,304
  float* sq           = (float*)(ws + 6389760);             //    32,768
  float* h_tanh       = (float*)(ws + 6422528);             // 4,194,304
  float* exp_att      = (float*)(ws + 10616832);            //   163,840
  float* colsum       = (float*)(ws + 10780672);            //        64
  float* bagU         = (float*)(ws + 10780736);            //     7,680

  hipMemsetAsync(ws + 10780672, 0, 64 + C_CLS * L_DIM * 4, stream);

  prep_x_kernel<<<2048, 256, 0, stream>>>(x, xbf, sq);
  prep_w_kernel<<<192, 256, 0, stream>>>(aW1, w1t);
  attn_gemm_kernel<<<64, 256, 0, stream>>>(xbf, w1t, ab1, h_tanh);
  attc_kernel<<<32, 256, 0, stream>>>(h_tanh, aW2, ab2, exp_att, colsum);
  bag_kernel<<<256, 256, 0, stream>>>(x, exp_att, bagU);
  final_kernel<<<1, 256, 0, stream>>>(bagU, colsum, cW1, cb1, cW2, cb2, outp);
  head_kernel<<<2048, 256, 0, stream>>>(xbf, sq, outp);
  dist_kernel<<<4096, 256, 0, stream>>>(xbf, sq, outp);
}